// Round 1
// baseline (359.983 us; speedup 1.0000x reference)
//
#include <hip/hip_runtime.h>
#include <math.h>

// Problem constants (CoPE2d): B=8, HEADS=12, H=W=24, SEQ=576, D=64, NPOS=24
#define NBATCH 8
#define NH 12
#define HW 24
#define S 576
#define DD 64
#define P 24

#define NROWS (192 * NH * HW)   // 55296 rows per unit (x or y)
#define WBUF_ELEMS ((long)NROWS * P)  // 1,327,104 floats per unit

// ---------------------------------------------------------------------------
// Kernel 1: CoPE unit for x (blocks [0,216)) and y (blocks [216,432)).
// One thread per output row (n,h,l): computes 24 gates -> reverse cumsum ->
// 24 logits (64-dot each, pos_emb via uniform/scalar loads) -> interp gather.
// Also emits per-row sum-of-squares for the cdist Gram trick.
// ---------------------------------------------------------------------------
__global__ __launch_bounds__(256) void cope_kernel(
    const float* __restrict__ q,     // [8,12,576,64]
    const float* __restrict__ attn,  // [8,12,576,576]
    const float* __restrict__ Ex,    // [64,24]
    const float* __restrict__ Ey,    // [64,24]
    float* __restrict__ wxb,         // [55296,24]
    float* __restrict__ wyb,         // [55296,24]
    float* __restrict__ sqx,         // [55296]
    float* __restrict__ sqy)         // [55296]
{
    __shared__ float lds_logits[256][P + 1];  // pad 25: <=2-way bank aliasing
    const int tid = threadIdx.x;
    int gidx = blockIdx.x * 256 + tid;
    const bool is_y = gidx >= NROWS;
    if (is_y) gidx -= NROWS;

    // decode row id: gidx = (n*12 + h)*24 + l
    const int l  = gidx % 24;   // j for x-unit, i for y-unit
    const int t2 = gidx / 24;   // == n*12 + h  (this IS idx2 of the buggy reshape)
    const int h  = t2 % NH;
    const int n  = t2 / NH;
    // scrambled decode (faithful to reference's reshape-without-permute):
    const int bb = t2 / (NH * 24);
    const int hd = (t2 / 24) % NH;
    const int ii = t2 % 24;     // i for x-unit, j for y-unit

    const float* E = is_y ? Ey : Ex;
    long arow_off;
    int astr;
    if (!is_y) {
        // attn_x_flat[n,h,l=j,k] = attn[bb,hd, ii*24+l, ii*24+k]
        arow_off = ((long)(bb * NH + hd) * S + (ii * 24 + l)) * S + ii * 24;
        astr = 1;
    } else {
        // attn_y_flat[n,h,l=i,k] = attn[bb,hd, l*24+ii, k*24+ii]
        arow_off = ((long)(bb * NH + hd) * S + (l * 24 + ii)) * S + ii;
        astr = 24;
    }
    const float* arow = attn + arow_off;

    // q uses the PROPER decode of n (b = n/24)
    const int bq = n / 24, oq = n % 24;
    const int qr = is_y ? (l * 24 + oq) : (oq * 24 + l);
    const float* qrow = q + ((long)(bq * NH + h) * S + qr) * DD;

    // gates -> reverse cumsum
    float pos[P];
    #pragma unroll
    for (int k = 0; k < P; ++k) {
        const float a = arow[k * astr];
        pos[k] = 1.0f / (1.0f + __expf(-a));
    }
    #pragma unroll
    for (int k = P - 2; k >= 0; --k) pos[k] += pos[k + 1];

    // logits[p] = q . E[:,p]   (E index is thread-uniform -> scalar loads)
    float logits[P];
    #pragma unroll
    for (int p = 0; p < P; ++p) logits[p] = 0.0f;
    for (int d4 = 0; d4 < DD; d4 += 4) {
        const float4 qv = *(const float4*)(qrow + d4);
        const float qd[4] = {qv.x, qv.y, qv.z, qv.w};
        #pragma unroll
        for (int dd = 0; dd < 4; ++dd) {
            #pragma unroll
            for (int p = 0; p < P; ++p)
                logits[p] = fmaf(qd[dd], E[(d4 + dd) * P + p], logits[p]);
        }
    }

    // spill logits to own LDS slot for dynamic-index gather (no barrier needed)
    #pragma unroll
    for (int p = 0; p < P; ++p) lds_logits[tid][p] = logits[p];

    float* wb = (is_y ? wyb : wxb) + (long)gidx * P;
    float sq = 0.0f;
    #pragma unroll
    for (int k = 0; k < P; ++k) {
        const float pk  = fminf(pos[k], (float)(P - 1));
        const float pf  = floorf(pk);
        const int   ic  = (int)ceilf(pk);
        const int   ifl = (int)pf;
        const float w   = pk - pf;
        const float lc  = lds_logits[tid][ic];
        const float lf  = lds_logits[tid][ifl];
        const float o   = lc * w + lf * (1.0f - w);
        wb[k] = o;
        sq += o * o;
    }
    (is_y ? sqy : sqx)[gidx] = sq;
}

// ---------------------------------------------------------------------------
// Kernel 2: fused cdist_x, cdist_y and combine.
// grid (9, 9, 96): 64x64 output tile per block for matrix g = b*12+h.
// d2 = sq_n + sq_m - 2*dot (matches reference), clamp>0, sqrt, blend.
// LDS rows padded to 28 floats (112B, float4-aligned); m-mapping tx+16*b
// keeps LDS read conflicts <=2-way.
// ---------------------------------------------------------------------------
__global__ __launch_bounds__(256) void dist_kernel(
    const float* __restrict__ wxb,
    const float* __restrict__ wyb,
    const float* __restrict__ sqx,
    const float* __restrict__ sqy,
    const float* __restrict__ wxscalar,
    float* __restrict__ out)   // [8,12,576,576]
{
    __shared__ __align__(16) float Xn[64][28];
    __shared__ __align__(16) float Xm[64][28];
    __shared__ __align__(16) float Yn[64][28];
    __shared__ __align__(16) float Ym[64][28];
    __shared__ float sXn[64], sXm[64], sYn[64], sYm[64];

    const int tid = threadIdx.x;
    const int g   = blockIdx.z;
    const int bb  = g / NH, h = g % NH;
    const int tn0 = blockIdx.y * 64, tm0 = blockIdx.x * 64;
    const float wx = wxscalar[0];

    // Stage 64 X-rows (n-side and m-side) and 64 Y-rows each into LDS.
    // pe_x row r of g: wxb[(((bb*24 + r/24)*12 + h)*24 + r%24)*24 + d]
    // pe_y row r of g: wyb[(((bb*24 + r%24)*12 + h)*24 + r/24)*24 + d]
    for (int idx = tid; idx < 64 * 24; idx += 256) {
        const int rr = idx / 24, d = idx % 24;
        const int rn = tn0 + rr, rm = tm0 + rr;
        Xn[rr][d] = wxb[(((long)(bb * 24 + rn / 24) * NH + h) * 24 + rn % 24) * 24 + d];
        Xm[rr][d] = wxb[(((long)(bb * 24 + rm / 24) * NH + h) * 24 + rm % 24) * 24 + d];
        Yn[rr][d] = wyb[(((long)(bb * 24 + rn % 24) * NH + h) * 24 + rn / 24) * 24 + d];
        Ym[rr][d] = wyb[(((long)(bb * 24 + rm % 24) * NH + h) * 24 + rm / 24) * 24 + d];
    }
    {
        const int r = tid & 63;
        const int which = tid >> 6;
        const int rn = tn0 + r, rm = tm0 + r;
        if (which == 0)      sXn[r] = sqx[((long)(bb * 24 + rn / 24) * NH + h) * 24 + rn % 24];
        else if (which == 1) sXm[r] = sqx[((long)(bb * 24 + rm / 24) * NH + h) * 24 + rm % 24];
        else if (which == 2) sYn[r] = sqy[((long)(bb * 24 + rn % 24) * NH + h) * 24 + rn / 24];
        else                 sYm[r] = sqy[((long)(bb * 24 + rm % 24) * NH + h) * 24 + rm / 24];
    }
    __syncthreads();

    const int tx = tid & 15, ty = tid >> 4;
    float accX[4][4] = {{0.f}}, accY[4][4] = {{0.f}};

    #pragma unroll
    for (int d4 = 0; d4 < 24; d4 += 4) {
        float4 xn[4], xm[4], yn[4], ym[4];
        #pragma unroll
        for (int a = 0; a < 4; ++a) {
            xn[a] = *(const float4*)&Xn[ty * 4 + a][d4];
            yn[a] = *(const float4*)&Yn[ty * 4 + a][d4];
        }
        #pragma unroll
        for (int b = 0; b < 4; ++b) {
            xm[b] = *(const float4*)&Xm[tx + 16 * b][d4];
            ym[b] = *(const float4*)&Ym[tx + 16 * b][d4];
        }
        #pragma unroll
        for (int a = 0; a < 4; ++a) {
            #pragma unroll
            for (int b = 0; b < 4; ++b) {
                accX[a][b] += xn[a].x * xm[b].x + xn[a].y * xm[b].y
                            + xn[a].z * xm[b].z + xn[a].w * xm[b].w;
                accY[a][b] += yn[a].x * ym[b].x + yn[a].y * ym[b].y
                            + yn[a].z * ym[b].z + yn[a].w * ym[b].w;
            }
        }
    }

    const float wyc = 1.0f - wx;
    #pragma unroll
    for (int a = 0; a < 4; ++a) {
        const int nn = ty * 4 + a;
        const float sxn = sXn[nn], syn = sYn[nn];
        const long ob = ((long)g * S + (tn0 + nn)) * S + tm0;
        #pragma unroll
        for (int b = 0; b < 4; ++b) {
            const int mm = tx + 16 * b;
            const float d2x = sxn + sXm[mm] - 2.0f * accX[a][b];
            const float d2y = syn + sYm[mm] - 2.0f * accY[a][b];
            const float dx = d2x > 0.0f ? sqrtf(d2x) : 0.0f;
            const float dy = d2y > 0.0f ? sqrtf(d2y) : 0.0f;
            out[ob + mm] = wx * dx + wyc * dy;
        }
    }
}

// ---------------------------------------------------------------------------
extern "C" void kernel_launch(void* const* d_in, const int* in_sizes, int n_in,
                              void* d_out, int out_size, void* d_ws, size_t ws_size,
                              hipStream_t stream) {
    const float* q    = (const float*)d_in[0];  // query [8,12,576,64]
    const float* attn = (const float*)d_in[1];  // attn_logits [8,12,576,576]
    const float* Ex   = (const float*)d_in[2];  // pos_emb_x [64,24]
    const float* Ey   = (const float*)d_in[3];  // pos_emb_y [64,24]
    const float* wxp  = (const float*)d_in[4];  // scalar
    float* out = (float*)d_out;

    // workspace: wxb | wyb | sqx | sqy  = 2*1327104 + 2*55296 floats ~ 11.06 MB
    float* ws  = (float*)d_ws;
    float* wxb = ws;
    float* wyb = wxb + WBUF_ELEMS;
    float* sqx = wyb + WBUF_ELEMS;
    float* sqy = sqx + NROWS;

    // 2*55296 rows / 256 = 432 blocks (exact)
    cope_kernel<<<432, 256, 0, stream>>>(q, attn, Ex, Ey, wxb, wyb, sqx, sqy);

    dim3 g2(9, 9, 96);
    dist_kernel<<<g2, 256, 0, stream>>>(wxb, wyb, sqx, sqy, wxp, out);
}

// Round 2
// 336.975 us; speedup vs baseline: 1.0683x; 1.0683x over previous
//
#include <hip/hip_runtime.h>
#include <math.h>

// CoPE2d: B=8, HEADS=12, H=W=24, SEQ=576, D=64, NPOS=24
#define NH 12
#define S 576
#define DD 64
#define P 24
#define NROWS 55296                    // rows per unit (x or y)
#define GELEMS ((long)NROWS * P)       // 1,327,104

typedef unsigned int uint;
typedef unsigned short ushort16;
typedef __bf16 bf16x8 __attribute__((ext_vector_type(8)));
typedef float f32x4 __attribute__((ext_vector_type(4)));

// ---------------------------------------------------------------------------
// Kernel 0: coalesced gather. Stream attn rows; each row r of (bb,hd)
// contributes one contiguous 24-slice to gx (x diag block) and one stride-24
// comb to gy. Reads 127 MB coalesced, writes 10.6 MB coalesced.
// ---------------------------------------------------------------------------
__global__ __launch_bounds__(256) void gather_kernel(
    const float* __restrict__ attn, float* __restrict__ gx, float* __restrict__ gy)
{
    __shared__ float rb[4][580];
    const int tid = threadIdx.x;
    const int r0 = blockIdx.x * 4;
    const int hd = blockIdx.y, bb = blockIdx.z;
    const long base = ((long)(bb * NH + hd) * S + r0) * S;
    for (int i = tid; i < 4 * S; i += 256)
        rb[i / S][i % S] = attn[base + i];
    __syncthreads();
    if (tid < 192) {
        const int row = tid / 48, j = tid % 48;
        const int r = r0 + row;
        const int band = r / 24, off = r % 24;   // r = band*24 + off
        if (j < 24) {
            // x: attn[.., band*24+off, band*24+j] -> gx[(bb*288+hd*24+band)*24+off][j]
            gx[((long)(bb * 288 + hd * 24 + band) * 24 + off) * 24 + j] =
                rb[row][band * 24 + j];
        } else {
            const int k = j - 24;
            // y: attn[.., band*24+off, k*24+off] -> gy[(bb*288+hd*24+off)*24+band][k]
            gy[((long)(bb * 288 + hd * 24 + off) * 24 + band) * 24 + k] =
                rb[row][k * 24 + off];
        }
    }
}

// ---------------------------------------------------------------------------
// Kernel 1: CoPE unit, now reading compact coalesced gate rows.
// Emits split-bf16 (hi,lo) rows + fp32 sq-norms for the MFMA Gram kernel.
// ---------------------------------------------------------------------------
__global__ __launch_bounds__(256) void cope_kernel(
    const float* __restrict__ q,
    const float* __restrict__ gx, const float* __restrict__ gy,
    const float* __restrict__ Ex, const float* __restrict__ Ey,
    ushort16* __restrict__ hibx, ushort16* __restrict__ lobx,
    ushort16* __restrict__ hiby, ushort16* __restrict__ loby,
    float* __restrict__ sqx, float* __restrict__ sqy)
{
    __shared__ float lds_logits[256][P + 1];
    const int tid = threadIdx.x;
    int gidx = blockIdx.x * 256 + tid;
    const bool is_y = gidx >= NROWS;
    if (is_y) gidx -= NROWS;

    const int l  = gidx % 24;
    const int t2 = gidx / 24;
    const int h  = t2 % NH;
    const int n  = t2 / NH;

    const float* E    = is_y ? Ey : Ex;
    const float* grow = (is_y ? gy : gx) + (long)gidx * P;
    const int bq = n / 24, oq = n % 24;
    const int qr = is_y ? (l * 24 + oq) : (oq * 24 + l);
    const float* qrow = q + ((long)(bq * NH + h) * S + qr) * DD;

    // gates (coalesced float4) -> sigmoid -> reverse cumsum
    float pos[P];
    #pragma unroll
    for (int k4 = 0; k4 < P; k4 += 4) {
        const float4 g4 = *(const float4*)(grow + k4);
        pos[k4 + 0] = 1.0f / (1.0f + __expf(-g4.x));
        pos[k4 + 1] = 1.0f / (1.0f + __expf(-g4.y));
        pos[k4 + 2] = 1.0f / (1.0f + __expf(-g4.z));
        pos[k4 + 3] = 1.0f / (1.0f + __expf(-g4.w));
    }
    #pragma unroll
    for (int k = P - 2; k >= 0; --k) pos[k] += pos[k + 1];

    // logits[p] = q . E[:,p]  (E index thread-uniform -> scalar loads)
    float logits[P];
    #pragma unroll
    for (int p = 0; p < P; ++p) logits[p] = 0.0f;
    for (int d4 = 0; d4 < DD; d4 += 4) {
        const float4 qv = *(const float4*)(qrow + d4);
        const float qd[4] = {qv.x, qv.y, qv.z, qv.w};
        #pragma unroll
        for (int dd = 0; dd < 4; ++dd) {
            #pragma unroll
            for (int p = 0; p < P; ++p)
                logits[p] = fmaf(qd[dd], E[(d4 + dd) * P + p], logits[p]);
        }
    }
    #pragma unroll
    for (int p = 0; p < P; ++p) lds_logits[tid][p] = logits[p];

    ushort16 hs[P], ls[P];
    float sq = 0.0f;
    #pragma unroll
    for (int k = 0; k < P; ++k) {
        const float pk  = fminf(pos[k], (float)(P - 1));
        const float pf  = floorf(pk);
        const int   ic  = (int)ceilf(pk);
        const int   ifl = (int)pf;
        const float w   = pk - pf;
        const float o   = lds_logits[tid][ic] * w + lds_logits[tid][ifl] * (1.0f - w);
        // split-bf16: hi = rne(o), lo = rne(o - hi)
        const uint ub = __float_as_uint(o);
        const uint rh = ub + 0x7FFFu + ((ub >> 16) & 1u);
        hs[k] = (ushort16)(rh >> 16);
        const float hif = __uint_as_float(rh & 0xFFFF0000u);
        const float lo  = o - hif;
        const uint ul = __float_as_uint(lo);
        const uint rl = ul + 0x7FFFu + ((ul >> 16) & 1u);
        ls[k] = (ushort16)(rl >> 16);
        sq += o * o;
    }
    // pack + coalesced 16B stores (row = 24 bf16 = 48 B)
    uint hu[12], lu[12];
    #pragma unroll
    for (int i = 0; i < 12; ++i) {
        hu[i] = (uint)hs[2 * i] | ((uint)hs[2 * i + 1] << 16);
        lu[i] = (uint)ls[2 * i] | ((uint)ls[2 * i + 1] << 16);
    }
    uint4* hb = (uint4*)((is_y ? hiby : hibx) + (long)gidx * P);
    uint4* lb = (uint4*)((is_y ? loby : lobx) + (long)gidx * P);
    hb[0] = make_uint4(hu[0], hu[1], hu[2], hu[3]);
    hb[1] = make_uint4(hu[4], hu[5], hu[6], hu[7]);
    hb[2] = make_uint4(hu[8], hu[9], hu[10], hu[11]);
    lb[0] = make_uint4(lu[0], lu[1], lu[2], lu[3]);
    lb[1] = make_uint4(lu[4], lu[5], lu[6], lu[7]);
    lb[2] = make_uint4(lu[8], lu[9], lu[10], lu[11]);
    (is_y ? sqy : sqx)[gidx] = sq;
}

// ---------------------------------------------------------------------------
// Kernel 2: MFMA Gram + cdist + combine. One wave per 64x64 output tile.
// dot = hi.hi + hi.lo + lo.hi (3 MFMAs, ~fp32-accurate); K=24 padded to 32.
// d2 = sq_n + sq_m - 2 dot; out = wx*sqrt(d2x) + (1-wx)*sqrt(d2y).
// ---------------------------------------------------------------------------
__device__ __forceinline__ int ixmap(int bb, int hd, int r) {
    return ((bb * 24 + r / 24) * NH + hd) * 24 + (r % 24);
}
__device__ __forceinline__ int iymap(int bb, int hd, int r) {
    return ((bb * 24 + r % 24) * NH + hd) * 24 + (r / 24);
}

__global__ __launch_bounds__(64) void dist_kernel(
    const ushort16* __restrict__ hibx, const ushort16* __restrict__ lobx,
    const ushort16* __restrict__ hiby, const ushort16* __restrict__ loby,
    const float* __restrict__ sqx, const float* __restrict__ sqy,
    const float* __restrict__ wxp, float* __restrict__ out)
{
    const int lane = threadIdx.x;
    const int lm = lane & 15, kg = lane >> 4;       // kg: k-group (C/D row quad)
    const int g = blockIdx.z, bb = g / NH, hd = g % NH;
    const int tn0 = blockIdx.y * 64, tm0 = blockIdx.x * 64;
    const float wx = wxp[0];

    bf16x8 zf;
    #pragma unroll
    for (int j = 0; j < 8; ++j) zf[j] = (__bf16)0.0f;

    bf16x8 ah[4], al[4], bh[4], bl[4];
    f32x4 dxa[4][4];   // X pass result -> dx; then Y acc in acc2

    // ---------------- X pass ----------------
    #pragma unroll
    for (int t = 0; t < 4; ++t) {
        ah[t] = zf; al[t] = zf; bh[t] = zf; bl[t] = zf;
        if (kg < 3) {
            const long oa = (long)ixmap(bb, hd, tn0 + t * 16 + lm) * P + kg * 8;
            ah[t] = *(const bf16x8*)(hibx + oa);
            al[t] = *(const bf16x8*)(lobx + oa);
            const long ob = (long)ixmap(bb, hd, tm0 + t * 16 + lm) * P + kg * 8;
            bh[t] = *(const bf16x8*)(hibx + ob);
            bl[t] = *(const bf16x8*)(lobx + ob);
        }
    }
    #pragma unroll
    for (int mt = 0; mt < 4; ++mt)
        #pragma unroll
        for (int nt = 0; nt < 4; ++nt) {
            f32x4 a = {0.f, 0.f, 0.f, 0.f};
            a = __builtin_amdgcn_mfma_f32_16x16x32_bf16(ah[mt], bh[nt], a, 0, 0, 0);
            a = __builtin_amdgcn_mfma_f32_16x16x32_bf16(ah[mt], bl[nt], a, 0, 0, 0);
            a = __builtin_amdgcn_mfma_f32_16x16x32_bf16(al[mt], bh[nt], a, 0, 0, 0);
            dxa[mt][nt] = a;
        }
    {
        float sn[4][4], sm[4];
        #pragma unroll
        for (int mt = 0; mt < 4; ++mt)
            #pragma unroll
            for (int rg = 0; rg < 4; ++rg)
                sn[mt][rg] = sqx[ixmap(bb, hd, tn0 + mt * 16 + kg * 4 + rg)];
        #pragma unroll
        for (int nt = 0; nt < 4; ++nt)
            sm[nt] = sqx[ixmap(bb, hd, tm0 + nt * 16 + lm)];
        #pragma unroll
        for (int mt = 0; mt < 4; ++mt)
            #pragma unroll
            for (int nt = 0; nt < 4; ++nt)
                #pragma unroll
                for (int rg = 0; rg < 4; ++rg) {
                    const float d2 = sn[mt][rg] + sm[nt] - 2.0f * dxa[mt][nt][rg];
                    dxa[mt][nt][rg] = d2 > 0.0f ? sqrtf(d2) : 0.0f;
                }
    }

    // ---------------- Y pass ----------------
    #pragma unroll
    for (int t = 0; t < 4; ++t) {
        ah[t] = zf; al[t] = zf; bh[t] = zf; bl[t] = zf;
        if (kg < 3) {
            const long oa = (long)iymap(bb, hd, tn0 + t * 16 + lm) * P + kg * 8;
            ah[t] = *(const bf16x8*)(hiby + oa);
            al[t] = *(const bf16x8*)(loby + oa);
            const long ob = (long)iymap(bb, hd, tm0 + t * 16 + lm) * P + kg * 8;
            bh[t] = *(const bf16x8*)(hiby + ob);
            bl[t] = *(const bf16x8*)(loby + ob);
        }
    }
    f32x4 acc2[4][4];
    #pragma unroll
    for (int mt = 0; mt < 4; ++mt)
        #pragma unroll
        for (int nt = 0; nt < 4; ++nt) {
            f32x4 a = {0.f, 0.f, 0.f, 0.f};
            a = __builtin_amdgcn_mfma_f32_16x16x32_bf16(ah[mt], bh[nt], a, 0, 0, 0);
            a = __builtin_amdgcn_mfma_f32_16x16x32_bf16(ah[mt], bl[nt], a, 0, 0, 0);
            a = __builtin_amdgcn_mfma_f32_16x16x32_bf16(al[mt], bh[nt], a, 0, 0, 0);
            acc2[mt][nt] = a;
        }
    float sn[4][4], sm[4];
    #pragma unroll
    for (int mt = 0; mt < 4; ++mt)
        #pragma unroll
        for (int rg = 0; rg < 4; ++rg)
            sn[mt][rg] = sqy[iymap(bb, hd, tn0 + mt * 16 + kg * 4 + rg)];
    #pragma unroll
    for (int nt = 0; nt < 4; ++nt)
        sm[nt] = sqy[iymap(bb, hd, tm0 + nt * 16 + lm)];

    const float wyc = 1.0f - wx;
    #pragma unroll
    for (int mt = 0; mt < 4; ++mt)
        #pragma unroll
        for (int rg = 0; rg < 4; ++rg) {
            const int row = tn0 + mt * 16 + kg * 4 + rg;
            const long ob = ((long)g * S + row) * S + tm0 + lm;
            #pragma unroll
            for (int nt = 0; nt < 4; ++nt) {
                const float d2 = sn[mt][rg] + sm[nt] - 2.0f * acc2[mt][nt][rg];
                const float dy = d2 > 0.0f ? sqrtf(d2) : 0.0f;
                out[ob + nt * 16] = wx * dxa[mt][nt][rg] + wyc * dy;
            }
        }
}

// ---------------------------------------------------------------------------
extern "C" void kernel_launch(void* const* d_in, const int* in_sizes, int n_in,
                              void* d_out, int out_size, void* d_ws, size_t ws_size,
                              hipStream_t stream) {
    const float* q    = (const float*)d_in[0];
    const float* attn = (const float*)d_in[1];
    const float* Ex   = (const float*)d_in[2];
    const float* Ey   = (const float*)d_in[3];
    const float* wxp  = (const float*)d_in[4];
    float* out = (float*)d_out;

    // workspace layout (~21.7 MB)
    float* gx = (float*)d_ws;
    float* gy = gx + GELEMS;
    ushort16* hibx = (ushort16*)(gy + GELEMS);
    ushort16* lobx = hibx + GELEMS;
    ushort16* hiby = lobx + GELEMS;
    ushort16* loby = hiby + GELEMS;
    float* sqx = (float*)(loby + GELEMS);
    float* sqy = sqx + NROWS;

    gather_kernel<<<dim3(144, NH, 8), 256, 0, stream>>>(attn, gx, gy);
    cope_kernel<<<432, 256, 0, stream>>>(q, gx, gy, Ex, Ey,
                                         hibx, lobx, hiby, loby, sqx, sqy);
    dist_kernel<<<dim3(9, 9, 96), 64, 0, stream>>>(hibx, lobx, hiby, loby,
                                                   sqx, sqy, wxp, out);
}

// Round 3
// 280.080 us; speedup vs baseline: 1.2853x; 1.2031x over previous
//
#include <hip/hip_runtime.h>
#include <math.h>

// CoPE2d: B=8, HEADS=12, H=W=24, SEQ=576, D=64, NPOS=24
#define NH 12
#define S 576
#define DD 64
#define P 24
#define NROWS 55296                 // rows per unit (x or y)
#define GELEMS ((long)NROWS * P)    // 1,327,104
#define PSTRIDE 32                  // padded bf16 row stride (64 B) for MFMA K=32

typedef unsigned int uint;
typedef unsigned short ushort;
typedef __bf16 bf16x8 __attribute__((ext_vector_type(8)));
typedef float f32x4 __attribute__((ext_vector_type(4)));

__device__ __forceinline__ uint bf16hi_bits(float v) {
    const uint u = __float_as_uint(v);
    return u + 0x7FFFu + ((u >> 16) & 1u);   // rne; take >>16 or &0xFFFF0000
}

// ---------------------------------------------------------------------------
// K0: streaming gather. 16 attn rows per block via float4, extract x-slice
// (contiguous 24) and y-comb (stride 24) into compact fp32 gate buffers.
// ---------------------------------------------------------------------------
__global__ __launch_bounds__(256) void gather_kernel(
    const float* __restrict__ attn, float* __restrict__ gx, float* __restrict__ gy)
{
    __shared__ float rb[16][580];
    const int tid = threadIdx.x;
    const int r0 = blockIdx.x * 16;
    const int hd = blockIdx.y, bb = blockIdx.z;
    const float4* src = (const float4*)(attn + ((long)(bb * NH + hd) * S + r0) * S);
    #pragma unroll
    for (int it = 0; it < 9; ++it) {
        const int i = it * 256 + tid;            // i < 2304 float4s (16 rows)
        const int row = i / 144, c4 = i % 144;
        *(float4*)&rb[row][c4 * 4] = src[i];
    }
    __syncthreads();
    #pragma unroll
    for (int t = 0; t < 3; ++t) {
        const int e = t * 256 + tid;             // e < 768
        const int row = e / 48, jj = e % 48;
        const int r = r0 + row;
        const int band = r / 24, off = r % 24;
        if (jj < 24) {
            gx[((long)((bb * 288 + hd * 24 + band) * 24 + off)) * 24 + jj] =
                rb[row][band * 24 + jj];
        } else {
            const int k = jj - 24;
            gy[((long)((bb * 288 + hd * 24 + off) * 24 + band)) * 24 + k] =
                rb[row][k * 24 + off];
        }
    }
}

// ---------------------------------------------------------------------------
// K1: CoPE. 32 rows/block, 8 threads/row. Phase1: 3 logits/thread with
// LDS-transposed E. Phase2: gates -> width-8 suffix scan -> interp -> W LDS.
// Phase3: pack hi/lo bf16 rows (g-major, 32-stride, zero pad) + sq norms.
// ---------------------------------------------------------------------------
__global__ __launch_bounds__(256) void cope_kernel(
    const float* __restrict__ q,
    const float* __restrict__ gx, const float* __restrict__ gy,
    const float* __restrict__ Ex, const float* __restrict__ Ey,
    __bf16* __restrict__ pxh, __bf16* __restrict__ pxl,
    __bf16* __restrict__ pyh, __bf16* __restrict__ pyl,
    float* __restrict__ sqx, float* __restrict__ sqy)
{
    __shared__ float Et[24][68];   // E transposed: Et[p][d]
    __shared__ float Lr[32][28];   // logits per row
    __shared__ float Wr[32][28];   // interp outputs per row

    const int tid = threadIdx.x;
    const int rl = tid >> 3, j = tid & 7;
    const int gidx0 = blockIdx.x * 32;
    const bool is_y = gidx0 >= NROWS;           // block-uniform (55296 % 32 == 0)
    const int gu = gidx0 - (is_y ? NROWS : 0) + rl;

    // decode row id (unit-local): gu = (n*12 + h)*24 + l
    const int l  = gu % 24;
    const int t2 = gu / 24;
    const int h  = t2 % NH, n = t2 / NH;
    const int bq = n / 24, oq = n % 24;
    const int qr = is_y ? (l * 24 + oq) : (oq * 24 + l);
    const int g  = bq * NH + h;

    const float* E = is_y ? Ey : Ex;
    for (int i = tid; i < 1536; i += 256) {
        const int d = i / 24, p = i % 24;
        Et[p][d] = E[i];
    }
    __syncthreads();

    // ---- phase 1: logits for p in {j, j+8, j+16} ----
    const float* qrow = q + ((long)g * S + qr) * DD;
    float a0 = 0.f, a1 = 0.f, a2 = 0.f;
    const int p0 = j, p1 = j + 8, p2 = j + 16;
    #pragma unroll
    for (int d4 = 0; d4 < DD; d4 += 4) {
        const float4 qv = *(const float4*)(qrow + d4);
        const float4 e0 = *(const float4*)&Et[p0][d4];
        const float4 e1 = *(const float4*)&Et[p1][d4];
        const float4 e2 = *(const float4*)&Et[p2][d4];
        a0 = fmaf(qv.x, e0.x, fmaf(qv.y, e0.y, fmaf(qv.z, e0.z, fmaf(qv.w, e0.w, a0))));
        a1 = fmaf(qv.x, e1.x, fmaf(qv.y, e1.y, fmaf(qv.z, e1.z, fmaf(qv.w, e1.w, a1))));
        a2 = fmaf(qv.x, e2.x, fmaf(qv.y, e2.y, fmaf(qv.z, e2.z, fmaf(qv.w, e2.w, a2))));
    }
    Lr[rl][p0] = a0; Lr[rl][p1] = a1; Lr[rl][p2] = a2;
    __syncthreads();

    // ---- phase 2: gates -> suffix scan -> interp ----
    const float* grow = (is_y ? gy : gx) + (long)gu * P + 3 * j;
    float g0 = grow[0], g1 = grow[1], g2 = grow[2];
    g0 = 1.0f / (1.0f + __expf(-g0));
    g1 = 1.0f / (1.0f + __expf(-g1));
    g2 = 1.0f / (1.0f + __expf(-g2));
    const float s = g0 + g1 + g2;
    float T = s;                                  // inclusive suffix sum over 8 lanes
    #pragma unroll
    for (int d = 1; d < 8; d <<= 1) {
        const float o = __shfl_down(T, d, 8);
        T += (j + d < 8) ? o : 0.0f;
    }
    const float Exc = T - s;                      // exclusive suffix
    float posv[3];
    posv[0] = T;                                  // g0+g1+g2+Exc
    posv[1] = g1 + g2 + Exc;
    posv[2] = g2 + Exc;

    float sqp = 0.f;
    #pragma unroll
    for (int m = 0; m < 3; ++m) {
        const float pk  = fminf(posv[m], 23.0f);
        const float pf  = floorf(pk);
        const int   ic  = (int)ceilf(pk);
        const int   ifl = (int)pf;
        const float w   = pk - pf;
        const float o   = Lr[rl][ic] * w + Lr[rl][ifl] * (1.0f - w);
        Wr[rl][3 * j + m] = o;
        sqp += o * o;
    }
    #pragma unroll
    for (int d = 1; d < 8; d <<= 1) {
        const float o = __shfl_down(sqp, d, 8);
        sqp += (j + d < 8) ? o : 0.0f;
    }
    if (j == 0) (is_y ? sqy : sqx)[(long)g * S + qr] = sqp;
    __syncthreads();

    // ---- phase 3: pack hi/lo bf16, 16B per thread, zero the K-pad ----
    const int hl = tid >> 7, rem = tid & 127;
    const int r3 = rem >> 2, seg = rem & 3;
    const int gu3 = gidx0 - (is_y ? NROWS : 0) + r3;
    const int l3 = gu3 % 24, t23 = gu3 / 24;
    const int h3 = t23 % NH, n3 = t23 / NH;
    const int bq3 = n3 / 24, oq3 = n3 % 24;
    const int qr3 = is_y ? (l3 * 24 + oq3) : (oq3 * 24 + l3);
    const int g3 = bq3 * NH + h3;
    __bf16* dst = (is_y ? (hl ? pyl : pyh) : (hl ? pxl : pxh))
                  + ((long)g3 * S + qr3) * PSTRIDE + seg * 8;
    uint pk4[4] = {0u, 0u, 0u, 0u};
    if (seg < 3) {
        ushort hv[8];
        #pragma unroll
        for (int t = 0; t < 8; ++t) {
            const float o = Wr[r3][seg * 8 + t];
            const uint rh = bf16hi_bits(o);
            if (hl == 0) {
                hv[t] = (ushort)(rh >> 16);
            } else {
                const float hif = __uint_as_float(rh & 0xFFFF0000u);
                hv[t] = (ushort)(bf16hi_bits(o - hif) >> 16);
            }
        }
        #pragma unroll
        for (int t = 0; t < 4; ++t)
            pk4[t] = (uint)hv[2 * t] | ((uint)hv[2 * t + 1] << 16);
    }
    *(uint4*)dst = make_uint4(pk4[0], pk4[1], pk4[2], pk4[3]);
}

// ---------------------------------------------------------------------------
// K2: MFMA Gram + cdist + blend. 256 threads = 4 waves = 4 consecutive
// 64x64 tiles of matrix g. Padded 64-B rows -> every frag load is a fully
// coalesced 1-KB wave load; addressing is add-only.
// ---------------------------------------------------------------------------
__global__ __launch_bounds__(256) void dist_kernel(
    const __bf16* __restrict__ pxh, const __bf16* __restrict__ pxl,
    const __bf16* __restrict__ pyh, const __bf16* __restrict__ pyl,
    const float* __restrict__ sqx, const float* __restrict__ sqy,
    const float* __restrict__ wxp, float* __restrict__ out)
{
    const int tid = threadIdx.x;
    const int w = tid >> 6, lane = tid & 63;
    const int til = blockIdx.x * 4 + w;
    if (til >= 81) return;
    const int g = blockIdx.y;
    const int tn = til / 9, tm = til % 9;
    const int lm = lane & 15, kg = lane >> 4;
    const float wx = wxp[0], wyc = 1.0f - wx;
    const long gb = (long)g * S;

    // persistent B frags (m-side): rows tm*64 + nt*16 + lm
    bf16x8 xbh[4], xbl[4], ybh[4], ybl[4];
    float smx[4], smy[4];
    #pragma unroll
    for (int nt = 0; nt < 4; ++nt) {
        const int row = tm * 64 + nt * 16 + lm;
        const long rb = (gb + row) * PSTRIDE + kg * 8;
        xbh[nt] = *(const bf16x8*)(pxh + rb);
        xbl[nt] = *(const bf16x8*)(pxl + rb);
        ybh[nt] = *(const bf16x8*)(pyh + rb);
        ybl[nt] = *(const bf16x8*)(pyl + rb);
        smx[nt] = sqx[gb + row];
        smy[nt] = sqy[gb + row];
    }

    #pragma unroll
    for (int mt = 0; mt < 4; ++mt) {
        const int arow = tn * 64 + mt * 16 + lm;
        const long ra = (gb + arow) * PSTRIDE + kg * 8;
        const bf16x8 xah = *(const bf16x8*)(pxh + ra);
        const bf16x8 xal = *(const bf16x8*)(pxl + ra);
        const bf16x8 yah = *(const bf16x8*)(pyh + ra);
        const bf16x8 yal = *(const bf16x8*)(pyl + ra);
        float snx[4], sny[4];
        #pragma unroll
        for (int rg = 0; rg < 4; ++rg) {
            const int r = tn * 64 + mt * 16 + kg * 4 + rg;
            snx[rg] = sqx[gb + r];
            sny[rg] = sqy[gb + r];
        }
        #pragma unroll
        for (int nt = 0; nt < 4; ++nt) {
            f32x4 ax = {0.f, 0.f, 0.f, 0.f};
            ax = __builtin_amdgcn_mfma_f32_16x16x32_bf16(xah, xbh[nt], ax, 0, 0, 0);
            ax = __builtin_amdgcn_mfma_f32_16x16x32_bf16(xah, xbl[nt], ax, 0, 0, 0);
            ax = __builtin_amdgcn_mfma_f32_16x16x32_bf16(xal, xbh[nt], ax, 0, 0, 0);
            f32x4 ay = {0.f, 0.f, 0.f, 0.f};
            ay = __builtin_amdgcn_mfma_f32_16x16x32_bf16(yah, ybh[nt], ay, 0, 0, 0);
            ay = __builtin_amdgcn_mfma_f32_16x16x32_bf16(yah, ybl[nt], ay, 0, 0, 0);
            ay = __builtin_amdgcn_mfma_f32_16x16x32_bf16(yal, ybh[nt], ay, 0, 0, 0);
            #pragma unroll
            for (int rg = 0; rg < 4; ++rg) {
                const int row = tn * 64 + mt * 16 + kg * 4 + rg;
                const int col = tm * 64 + nt * 16 + lm;
                const float d2x = fmaxf(fmaf(-2.0f, ax[rg], snx[rg] + smx[nt]), 0.0f);
                const float d2y = fmaxf(fmaf(-2.0f, ay[rg], sny[rg] + smy[nt]), 0.0f);
                const float dx = __builtin_amdgcn_sqrtf(d2x);
                const float dy = __builtin_amdgcn_sqrtf(d2y);
                out[(gb + row) * S + col] = fmaf(wx, dx, wyc * dy);
            }
        }
    }
}

// ---------------------------------------------------------------------------
extern "C" void kernel_launch(void* const* d_in, const int* in_sizes, int n_in,
                              void* d_out, int out_size, void* d_ws, size_t ws_size,
                              hipStream_t stream) {
    const float* q    = (const float*)d_in[0];
    const float* attn = (const float*)d_in[1];
    const float* Ex   = (const float*)d_in[2];
    const float* Ey   = (const float*)d_in[3];
    const float* wxp  = (const float*)d_in[4];
    float* out = (float*)d_out;

    // workspace: gx | gy (fp32 gates) | pxh|pxl|pyh|pyl (bf16, 32-stride) | sqx|sqy
    float* gx = (float*)d_ws;
    float* gy = gx + GELEMS;
    __bf16* pxh = (__bf16*)(gy + GELEMS);
    __bf16* pxl = pxh + (long)NROWS * PSTRIDE;
    __bf16* pyh = pxl + (long)NROWS * PSTRIDE;
    __bf16* pyl = pyh + (long)NROWS * PSTRIDE;
    float* sqx = (float*)(pyl + (long)NROWS * PSTRIDE);
    float* sqy = sqx + NROWS;

    gather_kernel<<<dim3(36, NH, 8), 256, 0, stream>>>(attn, gx, gy);
    cope_kernel<<<3456, 256, 0, stream>>>(q, gx, gy, Ex, Ey,
                                          pxh, pxl, pyh, pyl, sqx, sqy);
    dist_kernel<<<dim3(21, 96), 256, 0, stream>>>(pxh, pxl, pyh, pyl,
                                                  sqx, sqy, wxp, out);
}